// Round 11
// baseline (72.093 us; speedup 1.0000x reference)
//
#include <hip/hip_runtime.h>

typedef float f32x4 __attribute__((ext_vector_type(4)));

#define MDIM 8192
#define NDIM 8192
#define KDIM 64

#define BM 16
#define WROW 68   // wave-private LDS row stride in dwords (16 x 68 x 4B = 4.25 KB/wave)

__device__ __forceinline__ int pk4(float a, float b, float c, float d) {
    int r = __builtin_amdgcn_cvt_pk_fp8_f32(a, b, 0, false);
    return __builtin_amdgcn_cvt_pk_fp8_f32(c, d, r, true);
}

// ---- single fully-fused kernel: quantize (bounded-redundancy) + GEMM ----
// Grid 2048 = 64 M-groups x 32 N-slices (ns fastest), 256 threads, 4/CU.
// Block owns cols [ns*256,+256) x rows [mg*128,+128).
//   B: its 64x256 k-slice quantized ONCE into 8 register longs per lane
//      (lane (r,g) builds fragment (ks,g,r) of tiles w*4+n directly from 64
//      scalar loads of L2-resident k; x64 redundancy on 2 MB = absorbed).
//   A: per 16-row panel, lane-local quantize from q (2x16B loads, 4 pk4).
//   Epilogue: barrier-free wave-private LDS transpose (lgkmcnt only; stores
//   never drained inside the loop), 8 panels amortize everything.
__global__ __launch_bounds__(256, 4) void gemm_fused(const float* __restrict__ Q,
                                                     const float* __restrict__ K,
                                                     float* __restrict__ C) {
    __shared__ float lds[4 * BM * WROW];   // 17408 B

    const int w    = threadIdx.x >> 6;    // wave 0..3
    const int lane = threadIdx.x & 63;
    const int r    = lane & 15;
    const int g    = lane >> 4;

    const int b  = blockIdx.x;            // 0..2047
    const int ns = b & 31;                // N-slice (fastest -> write locality)
    const int mg = b >> 5;                // M-group
    const int colbase = ns * 256;
    const int rowgrp  = mg * 128;

    // ---- B fragments: quantize k-slice once into registers ----
    // Fragment (n,ks) for lane (r,g): col = colbase + w*64 + n*16 + r,
    // k-rows ks*32+g*8 .. +8. 8 scalar loads -> 2 pk4 -> 1 long.
    long bfr[4][2];
#pragma unroll
    for (int n = 0; n < 4; ++n) {
        const int col = colbase + w * 64 + n * 16 + r;
#pragma unroll
        for (int ks = 0; ks < 2; ++ks) {
            const int k0 = ks * 32 + g * 8;
            float v[8];
#pragma unroll
            for (int j = 0; j < 8; ++j)
                v[j] = K[(size_t)(k0 + j) * NDIM + col];
            int lo = pk4(v[0], v[1], v[2], v[3]);
            int hi = pk4(v[4], v[5], v[6], v[7]);
            bfr[n][ks] = ((long)(unsigned)hi << 32) | (unsigned)lo;
        }
    }

    float* wl = &lds[w * BM * WROW];

    // ---- 8 M-panels of 16 rows ----
    for (int mi = 0; mi < 8; ++mi) {
        const int rowbase = rowgrp + mi * 16;

        // A fragments: lane-local quantize (row rowbase + r).
        long a[2];
#pragma unroll
        for (int ks = 0; ks < 2; ++ks) {
            const f32x4* p = reinterpret_cast<const f32x4*>(
                &Q[(size_t)(rowbase + r) * KDIM + ks * 32 + g * 8]);
            f32x4 u0 = p[0], u1 = p[1];
            int lo = pk4(u0[0], u0[1], u0[2], u0[3]);
            int hi = pk4(u1[0], u1[1], u1[2], u1[3]);
            a[ks] = ((long)(unsigned)hi << 32) | (unsigned)lo;
        }

        f32x4 acc[4] = {};
#pragma unroll
        for (int n = 0; n < 4; ++n) {
            acc[n] = __builtin_amdgcn_mfma_f32_16x16x32_fp8_fp8(a[0], bfr[n][0], acc[n], 0, 0, 0);
            acc[n] = __builtin_amdgcn_mfma_f32_16x16x32_fp8_fp8(a[1], bfr[n][1], acc[n], 0, 0, 0);
        }

        // Wave-private stage. C/D layout: col = lane&15, row = g*4 + j.
        // Banks (16g + 4j + 16n + r) mod 32 -> 2-way (free).
#pragma unroll
        for (int n = 0; n < 4; ++n)
#pragma unroll
            for (int j = 0; j < 4; ++j)
                wl[(g * 4 + j) * WROW + n * 16 + r] = acc[n][j];

        // Wave-local ordering only — never touches vmcnt; stores from prior
        // panels stay in flight.
        __builtin_amdgcn_sched_barrier(0);
        asm volatile("s_waitcnt lgkmcnt(0)" ::: "memory");
        __builtin_amdgcn_sched_barrier(0);

        // Stream out: instr p writes rows 4p+g; 16 lanes/row -> 256 B segs.
#pragma unroll
        for (int p = 0; p < 4; ++p) {
            const int row = p * 4 + g;
            f32x4 v = *reinterpret_cast<const f32x4*>(&wl[row * WROW + 4 * r]);
            *reinterpret_cast<f32x4*>(
                &C[(size_t)(rowbase + row) * NDIM + colbase + w * 64 + 4 * r]) = v;
        }
    }
}

extern "C" void kernel_launch(void* const* d_in, const int* in_sizes, int n_in,
                              void* d_out, int out_size, void* d_ws, size_t ws_size,
                              hipStream_t stream) {
    const float* q = (const float*)d_in[0];   // [8192][64] fp32
    const float* k = (const float*)d_in[1];   // [64][8192] fp32
    float* C = (float*)d_out;                 // [8192][8192] fp32

    hipLaunchKernelGGL(gemm_fused, dim3(2048), dim3(256), 0, stream, q, k, C);
}

// Round 12
// 61.931 us; speedup vs baseline: 1.1641x; 1.1641x over previous
//
#include <hip/hip_runtime.h>

typedef float f32x4 __attribute__((ext_vector_type(4)));

#define MDIM 8192
#define NDIM 8192
#define KDIM 64

#define BM 16
#define BN 256
#define LSTR 258   // epilogue LDS row stride in dwords (16 x 258 x 4B = 16.5 KB)

// kT swizzled fragment layout (unchanged): per 16-col tile, 1024 B =
// [ks:2][g:4][r:16][8 B]; fragment load for lane (r,g): 8 B at tile*1024 +
// ks*512 + g*128 + r*8 -> 512 B contiguous per wave.

__device__ __forceinline__ int pk4(float a, float b, float c, float d) {
    int r = __builtin_amdgcn_cvt_pk_fp8_f32(a, b, 0, false);
    return __builtin_amdgcn_cvt_pk_fp8_f32(c, d, r, true);
}

// ---- prepass: quantize + transpose + swizzle k only ----
__global__ __launch_bounds__(256) void quant_k(const float* __restrict__ k,
                                               int2* __restrict__ k8s) {
    int qq = blockIdx.y;                             // k quarter 0..3
    int n  = blockIdx.x * 256 + threadIdx.x;         // column 0..8191
    int pk[4];
#pragma unroll
    for (int j = 0; j < 4; ++j) {
        int row = qq * 16 + j * 4;
        float v0 = k[(size_t)(row + 0) * NDIM + n];  // coalesced across lanes
        float v1 = k[(size_t)(row + 1) * NDIM + n];
        float v2 = k[(size_t)(row + 2) * NDIM + n];
        float v3 = k[(size_t)(row + 3) * NDIM + n];
        pk[j] = pk4(v0, v1, v2, v3);
    }
    int tile = n >> 4, r = n & 15, ks = qq >> 1, gb = (qq & 1) * 2;
    size_t base = (size_t)tile * 128 + ks * 64 + gb * 16 + r;  // int2 units
    k8s[base]      = make_int2(pk[0], pk[1]);
    k8s[base + 16] = make_int2(pk[2], pk[3]);
}

// ---------------- GEMM (R6 structure) with lane-local A-quantize ----------
// block = 256 threads (4 waves), tile 16(M) x 256(N), wave tile 16x64.
// A: quantized in-register from q (2x16B loads + 4 cvt_pk, lane-local).
// B: swizzled fp8 fragments from prepass (512 B contiguous per wave-load).
// Epilogue: LDS-staged block-wide rows, 1 KB contiguous per wave-store, nt.
__global__ __launch_bounds__(256, 8) void gemm_fp8(const float* __restrict__ Q,
                                                   const long* __restrict__ B8,
                                                   float* __restrict__ C) {
    __shared__ float lds[BM * LSTR];

    const int w    = threadIdx.x >> 6;    // wave 0..3 (N-slice w*64)
    const int lane = threadIdx.x & 63;
    const int r    = lane & 15;
    const int g    = lane >> 4;
    const int fs   = g * 16 + r;          // fragment slot (long units)

    const int bx = blockIdx.x;            // N tile (32) — fastest
    const int by = blockIdx.y;            // M tile (512)
    const int rowbase = by * BM;
    const int colbase = bx * BN;

    // A fragments: lane-local quantize of q row (rowbase + r).
    long a[2];
#pragma unroll
    for (int ks = 0; ks < 2; ++ks) {
        const f32x4* p = reinterpret_cast<const f32x4*>(
            &Q[(size_t)(rowbase + r) * KDIM + ks * 32 + g * 8]);
        f32x4 u0 = p[0], u1 = p[1];
        int lo = pk4(u0[0], u0[1], u0[2], u0[3]);
        int hi = pk4(u1[0], u1[1], u1[2], u1[3]);
        a[ks] = ((long)(unsigned)hi << 32) | (unsigned)lo;
    }

    long b[4][2];
#pragma unroll
    for (int n = 0; n < 4; ++n)
#pragma unroll
        for (int ks = 0; ks < 2; ++ks)
            b[n][ks] = B8[(size_t)((colbase >> 4) + w * 4 + n) * 128 + ks * 64 + fs];

    f32x4 acc[4] = {};
#pragma unroll
    for (int n = 0; n < 4; ++n) {
        acc[n] = __builtin_amdgcn_mfma_f32_16x16x32_fp8_fp8(a[0], b[n][0], acc[n], 0, 0, 0);
        acc[n] = __builtin_amdgcn_mfma_f32_16x16x32_fp8_fp8(a[1], b[n][1], acc[n], 0, 0, 0);
    }

    // Stage in LDS. C/D layout: col = lane&15, row = g*4 + i.
#pragma unroll
    for (int n = 0; n < 4; ++n) {
        const int col = w * 64 + n * 16 + r;
#pragma unroll
        for (int i = 0; i < 4; ++i)
            lds[(g * 4 + i) * LSTR + col] = acc[n][i];
    }

    __syncthreads();

    // Stream out: each wave writes one full 1 KB contiguous row per round.
#pragma unroll
    for (int p = 0; p < 4; ++p) {
        const int row  = p * 4 + w;
        const int col4 = lane * 4;
        f32x4 v = *reinterpret_cast<const f32x4*>(&lds[row * LSTR + col4]);
        __builtin_nontemporal_store(
            v, reinterpret_cast<f32x4*>(&C[(size_t)(rowbase + row) * NDIM + colbase + col4]));
    }
}

extern "C" void kernel_launch(void* const* d_in, const int* in_sizes, int n_in,
                              void* d_out, int out_size, void* d_ws, size_t ws_size,
                              hipStream_t stream) {
    const float* q = (const float*)d_in[0];   // [8192][64] fp32
    const float* k = (const float*)d_in[1];   // [64][8192] fp32
    float* C = (float*)d_out;                 // [8192][8192] fp32

    long* k8s = (long*)d_ws;                  // 512 KB swizzled kT fp8

    hipLaunchKernelGGL(quant_k, dim3(32, 4), dim3(256), 0, stream, k, (int2*)k8s);
    hipLaunchKernelGGL(gemm_fp8, dim3(NDIM / BN, MDIM / BM), dim3(256), 0, stream,
                       q, (const long*)k8s, C);
}

// Round 13
// 49.086 us; speedup vs baseline: 1.4687x; 1.2617x over previous
//
#include <hip/hip_runtime.h>

typedef float f32x4 __attribute__((ext_vector_type(4)));

#define MDIM 8192
#define NDIM 8192
#define KDIM 64

#define BM 16
#define BN 256
#define LSTR 258   // epilogue LDS row stride in dwords (16 x 258 x 4B = 16.5 KB)

// Swizzled fp8 fragment layout, both operands:
//   per 16-row(col) tile: 1024 B = [ks:2][g:4][r:16][8 B]; the 8 B at (ks,g,r)
//   are k = ks*32+g*8 .. +8 of row(col) r. Fragment load for lane (r,g):
//   8 B at tile*1024 + ks*512 + g*128 + r*8 -> 512 B contiguous per wave.

__device__ __forceinline__ int pk4(float a, float b, float c, float d) {
    int r = __builtin_amdgcn_cvt_pk_fp8_f32(a, b, 0, false);
    return __builtin_amdgcn_cvt_pk_fp8_f32(c, d, r, true);
}

// ---- fused quantize: blocks [0,128) -> q path, [128,256) -> k path ----
__global__ __launch_bounds__(256) void quant_both(const float* __restrict__ q,
                                                  const float* __restrict__ k,
                                                  int2* __restrict__ q8s,
                                                  int2* __restrict__ k8s) {
    const int bid = blockIdx.x;
    if (bid < 128) {
        // q [8192][64] row-major: thread t handles 16 consecutive floats
        // = row m = t>>2, quarter qq = t&3 (k-range qq*16..+16).
        int t = bid * 256 + threadIdx.x;                 // 32768 threads
        const float4* p = reinterpret_cast<const float4*>(q) + (size_t)t * 4;
        float4 v0 = p[0], v1 = p[1], v2 = p[2], v3 = p[3];
        int p0 = pk4(v0.x, v0.y, v0.z, v0.w);
        int p1 = pk4(v1.x, v1.y, v1.z, v1.w);
        int p2 = pk4(v2.x, v2.y, v2.z, v2.w);
        int p3 = pk4(v3.x, v3.y, v3.z, v3.w);
        int m = t >> 2, qq = t & 3;
        int tile = m >> 4, r = m & 15, ks = qq >> 1, gb = (qq & 1) * 2;
        size_t base = (size_t)tile * 128 + ks * 64 + gb * 16 + r;  // int2 units
        q8s[base]      = make_int2(p0, p1);
        q8s[base + 16] = make_int2(p2, p3);
    } else {
        // k [64][8192] row-major: thread handles col n, quarter qq
        int bb = bid - 128;
        int qq = bb & 3;
        int n  = (bb >> 2) * 256 + threadIdx.x;          // column 0..8191
        int pk[4];
#pragma unroll
        for (int j = 0; j < 4; ++j) {
            int row = qq * 16 + j * 4;
            float v0 = k[(size_t)(row + 0) * NDIM + n];  // coalesced across lanes
            float v1 = k[(size_t)(row + 1) * NDIM + n];
            float v2 = k[(size_t)(row + 2) * NDIM + n];
            float v3 = k[(size_t)(row + 3) * NDIM + n];
            pk[j] = pk4(v0, v1, v2, v3);
        }
        int tile = n >> 4, r = n & 15, ks = qq >> 1, gb = (qq & 1) * 2;
        size_t base = (size_t)tile * 128 + ks * 64 + gb * 16 + r;
        k8s[base]      = make_int2(pk[0], pk[1]);
        k8s[base + 16] = make_int2(pk[2], pk[3]);
    }
}

// ---------------- GEMM: C[M][N] = A * B, swizzled fp8 operands ----------
// block = 256 threads (4 waves), tile 16(M) x 256(N), wave tile 16x64.
// Small tile + __launch_bounds__(256,8): <=64 VGPR -> 32 waves/CU
// -> 8 resident blocks/CU for deep overlap of prologues with other
// blocks' store streams.
__global__ __launch_bounds__(256, 8) void gemm_fp8(const long* __restrict__ A8,
                                                   const long* __restrict__ B8,
                                                   float* __restrict__ C) {
    __shared__ float lds[BM * LSTR];

    const int w    = threadIdx.x >> 6;    // wave 0..3 (N-slice w*64)
    const int lane = threadIdx.x & 63;
    const int r    = lane & 15;
    const int g    = lane >> 4;
    const int fs   = g * 16 + r;          // fragment slot within tile (long units)

    const int bx = blockIdx.x;            // N tile (32)
    const int by = blockIdx.y;            // M tile (512)
    const int rowbase = by * BM;
    const int colbase = bx * BN;

    long a[2];
#pragma unroll
    for (int ks = 0; ks < 2; ++ks)
        a[ks] = A8[(size_t)by * 128 + ks * 64 + fs];

    long b[4][2];
#pragma unroll
    for (int n = 0; n < 4; ++n)
#pragma unroll
        for (int ks = 0; ks < 2; ++ks)
            b[n][ks] = B8[(size_t)((colbase >> 4) + w * 4 + n) * 128 + ks * 64 + fs];

    f32x4 acc[4] = {};
#pragma unroll
    for (int n = 0; n < 4; ++n) {
        acc[n] = __builtin_amdgcn_mfma_f32_16x16x32_fp8_fp8(a[0], b[n][0], acc[n], 0, 0, 0);
        acc[n] = __builtin_amdgcn_mfma_f32_16x16x32_fp8_fp8(a[1], b[n][1], acc[n], 0, 0, 0);
    }

    // Stage in LDS. C/D layout: col = lane&15, row = g*4 + i.
    // Writes: banks r + 8g pattern -> <=2-way (free). Reads: one row/wave,
    // 1 KB contiguous -> conflict-free.
#pragma unroll
    for (int n = 0; n < 4; ++n) {
        const int col = w * 64 + n * 16 + r;
#pragma unroll
        for (int i = 0; i < 4; ++i)
            lds[(g * 4 + i) * LSTR + col] = acc[n][i];
    }

    __syncthreads();

    // Stream out: each wave writes one full 1 KB row per round.
#pragma unroll
    for (int p = 0; p < 4; ++p) {
        const int row  = p * 4 + w;
        const int col4 = lane * 4;
        f32x4 v = *reinterpret_cast<const f32x4*>(&lds[row * LSTR + col4]);
        __builtin_nontemporal_store(
            v, reinterpret_cast<f32x4*>(&C[(size_t)(rowbase + row) * NDIM + colbase + col4]));
    }
}

extern "C" void kernel_launch(void* const* d_in, const int* in_sizes, int n_in,
                              void* d_out, int out_size, void* d_ws, size_t ws_size,
                              hipStream_t stream) {
    const float* q = (const float*)d_in[0];   // [8192][64] fp32
    const float* k = (const float*)d_in[1];   // [64][8192] fp32
    float* C = (float*)d_out;                 // [8192][8192] fp32

    long* q8s = (long*)d_ws;                                  // 512 KB swizzled A
    long* k8s = q8s + (size_t)MDIM * KDIM / 8;                // 512 KB swizzled B

    hipLaunchKernelGGL(quant_both, dim3(256), dim3(256), 0, stream,
                       q, k, (int2*)q8s, (int2*)k8s);
    hipLaunchKernelGGL(gemm_fp8, dim3(NDIM / BN, MDIM / BM), dim3(256), 0, stream,
                       (const long*)q8s, (const long*)k8s, C);
}